// Round 2
// baseline (49.623 us; speedup 1.0000x reference)
//
#include <hip/hip_runtime.h>

constexpr int NUM_SKILLS = 300;
constexpr int EMB = 256;
constexpr int CD  = 64;
constexpr int D3  = 21;   // CURVE_DIM // 3
constexpr int DM  = 22;   // D3 + CURVE_DIM % 3
constexpr int SEQ = 200;

// d_ws layout (floats):
//   [0, 1024)          : coefficients  A[e]=cf[e], B[e]=cf[256+e], C[e]=cf[512+e], D[e]=cf[768+e]
//   [1024, 1024+B*S*4) : per-(b,t) state float4 {skill, attempts, mastery, valid}
constexpr int COEF_FLOATS = 1024;

// Kernel 1: per-row running counts (one block per batch row) + coefficient fold (block 0).
__global__ __launch_bounds__(256)
void traj_prep_kernel(const int* __restrict__ q, const int* __restrict__ r,
                      const float* __restrict__ skill_w, const float* __restrict__ skill_b,
                      const float* __restrict__ att_w,   const float* __restrict__ att_b,
                      const float* __restrict__ mast_w,  const float* __restrict__ mast_b,
                      const float* __restrict__ proj_w,  const float* __restrict__ proj_b,
                      float* __restrict__ coef, float4* __restrict__ state)
{
    __shared__ int s_q[SEQ], s_r[SEQ];
    const int tid = threadIdx.x;
    const int b   = blockIdx.x;

    if (tid < SEQ) {
        s_q[tid] = q[b * SEQ + tid];
        s_r[tid] = r[b * SEQ + tid];
    }

    if (b == 0) {
        // Fold the three scalar encoders + biases: traj[e] = sk*A + att*B + mast*C + D
        const float* pw = proj_w + tid * CD;
        float ca = 0.f, cb = 0.f, cc = 0.f, cd = 0.f;
        #pragma unroll
        for (int i = 0; i < D3; ++i) { float w = pw[i];        ca = fmaf(w, skill_w[i], ca); cd = fmaf(w, skill_b[i], cd); }
        #pragma unroll
        for (int i = 0; i < D3; ++i) { float w = pw[D3 + i];   cb = fmaf(w, att_w[i],  cb);  cd = fmaf(w, att_b[i],  cd); }
        #pragma unroll
        for (int i = 0; i < DM; ++i) { float w = pw[2*D3 + i]; cc = fmaf(w, mast_w[i], cc);  cd = fmaf(w, mast_b[i], cd); }
        coef[tid]       = ca;
        coef[256 + tid] = cb;
        coef[512 + tid] = cc;
        coef[768 + tid] = cd + proj_b[tid];
    }
    __syncthreads();

    if (tid < SEQ) {
        const int myq = s_q[tid];
        const bool v  = (myq >= 0) && (myq < NUM_SKILLS);
        int cnt = 0, cor = 0;
        for (int t = 0; t <= tid; ++t) {
            const int qt = s_q[t];
            const bool m = (qt == myq) && v;   // qt==myq && myq valid => qt valid
            cnt += m ? 1 : 0;
            cor += m ? s_r[t] : 0;
        }
        const float att = (float)cnt;
        float4 st;
        st.x = (float)myq;
        st.y = att;
        st.z = (float)cor / fmaxf(att, 1.0f);
        st.w = v ? 1.0f : 0.0f;
        state[b * SEQ + tid] = st;
    }
}

// Kernel 2: pure streaming affine store. Each block: one (batch, 100-row half).
// Thread (e4, ssub): 4 consecutive emb channels, rows s_base+s0+ssub.
__global__ __launch_bounds__(256)
void traj_store_kernel(const float* __restrict__ coef, const float4* __restrict__ state,
                       float4* __restrict__ out4)
{
    const int tid  = threadIdx.x;
    const int e4   = tid & 63;
    const int ssub = tid >> 6;
    const int b      = blockIdx.x >> 1;
    const int s_base = (blockIdx.x & 1) * (SEQ / 2);

    const float4* c4 = reinterpret_cast<const float4*>(coef);
    const float4 A4 = c4[e4];
    const float4 B4 = c4[64  + e4];
    const float4 C4 = c4[128 + e4];
    const float4 D4 = c4[192 + e4];

    const float4* __restrict__ st = state + b * SEQ;
    float4* __restrict__ o = out4 + (size_t)b * SEQ * (EMB / 4);

    #pragma unroll 5
    for (int s0 = 0; s0 < SEQ / 2; s0 += 4) {
        const int s = s_base + s0 + ssub;
        const float4 t = st[s];           // uniform per wave
        float4 o4;
        o4.x = t.w * fmaf(t.x, A4.x, fmaf(t.y, B4.x, fmaf(t.z, C4.x, D4.x)));
        o4.y = t.w * fmaf(t.x, A4.y, fmaf(t.y, B4.y, fmaf(t.z, C4.y, D4.y)));
        o4.z = t.w * fmaf(t.x, A4.z, fmaf(t.y, B4.z, fmaf(t.z, C4.z, D4.z)));
        o4.w = t.w * fmaf(t.x, A4.w, fmaf(t.y, B4.w, fmaf(t.z, C4.w, D4.w)));
        o[(size_t)s * (EMB / 4) + e4] = o4;
    }
}

extern "C" void kernel_launch(void* const* d_in, const int* in_sizes, int n_in,
                              void* d_out, int out_size, void* d_ws, size_t ws_size,
                              hipStream_t stream)
{
    const int* q        = (const int*)d_in[0];
    const int* r        = (const int*)d_in[1];
    // d_in[2] = qry (unused by the reference)
    const float* skill_w = (const float*)d_in[3];
    const float* skill_b = (const float*)d_in[4];
    const float* att_w   = (const float*)d_in[5];
    const float* att_b   = (const float*)d_in[6];
    const float* mast_w  = (const float*)d_in[7];
    const float* mast_b  = (const float*)d_in[8];
    const float* proj_w  = (const float*)d_in[9];
    const float* proj_b  = (const float*)d_in[10];
    float* out = (float*)d_out;

    const int B = in_sizes[0] / SEQ;  // 512

    float*  coef  = (float*)d_ws;
    float4* state = reinterpret_cast<float4*>((float*)d_ws + COEF_FLOATS);

    traj_prep_kernel<<<B, 256, 0, stream>>>(q, r, skill_w, skill_b, att_w, att_b,
                                            mast_w, mast_b, proj_w, proj_b, coef, state);
    traj_store_kernel<<<B * 2, 256, 0, stream>>>(coef, state,
                                                 reinterpret_cast<float4*>(out));
}

// Round 3
// 31.491 us; speedup vs baseline: 1.5758x; 1.5758x over previous
//
#include <hip/hip_runtime.h>

constexpr int NUM_SKILLS = 300;
constexpr int EMB = 256;
constexpr int CD  = 64;
constexpr int D3  = 21;   // CURVE_DIM // 3
constexpr int DM  = 22;   // D3 + CURVE_DIM % 3
constexpr int SEQ = 200;

typedef float vf4 __attribute__((ext_vector_type(4)));

__global__ __launch_bounds__(256)
void traj_enc_kernel(const int* __restrict__ q, const int* __restrict__ r,
                     const float* __restrict__ skill_w, const float* __restrict__ skill_b,
                     const float* __restrict__ att_w,   const float* __restrict__ att_b,
                     const float* __restrict__ mast_w,  const float* __restrict__ mast_b,
                     const float* __restrict__ proj_w,  const float* __restrict__ proj_b,
                     float* __restrict__ out)
{
    __shared__ __align__(16) float sA[EMB];
    __shared__ __align__(16) float sB[EMB];
    __shared__ __align__(16) float sC[EMB];
    __shared__ __align__(16) float sD[EMB];
    __shared__ float s_skill[SEQ], s_att[SEQ], s_mast[SEQ], s_valid[SEQ];
    __shared__ int   s_q[SEQ], s_r[SEQ];

    const int tid = threadIdx.x;
    const int b   = blockIdx.x;

    // stage this batch's q/r rows
    if (tid < SEQ) {
        s_q[tid] = q[b * SEQ + tid];
        s_r[tid] = r[b * SEQ + tid];
    }

    // Phase 0: fold the three scalar encoders + biases into per-e coefficients.
    // traj[e] = skill*A[e] + attempts*B[e] + mastery*C[e] + D[e]
    {
        const float* pw = proj_w + tid * CD;
        float ca = 0.f, cb = 0.f, cc = 0.f, cd = 0.f;
        #pragma unroll
        for (int i = 0; i < D3; ++i) { float w = pw[i];        ca = fmaf(w, skill_w[i], ca); cd = fmaf(w, skill_b[i], cd); }
        #pragma unroll
        for (int i = 0; i < D3; ++i) { float w = pw[D3 + i];   cb = fmaf(w, att_w[i],  cb);  cd = fmaf(w, att_b[i],  cd); }
        #pragma unroll
        for (int i = 0; i < DM; ++i) { float w = pw[2*D3 + i]; cc = fmaf(w, mast_w[i], cc);  cd = fmaf(w, mast_b[i], cd); }
        sA[tid] = ca; sB[tid] = cb; sC[tid] = cc; sD[tid] = cd + proj_b[tid];
    }
    __syncthreads();

    // Phase 1: running counts. attempts[t] = #{t'<=t : valid(q[t']) && q[t']==q[t]}
    if (tid < SEQ) {
        const int myq = s_q[tid];
        const bool v  = (myq >= 0) && (myq < NUM_SKILLS);
        int cnt = 0, cor = 0;
        for (int t = 0; t <= tid; ++t) {
            const int qt = s_q[t];
            const bool m = (qt == myq) && v;
            cnt += m ? 1 : 0;
            cor += m ? s_r[t] : 0;
        }
        const float att = (float)cnt;
        s_skill[tid] = (float)myq;
        s_att[tid]   = att;
        s_mast[tid]  = (float)cor / fmaxf(att, 1.0f);
        s_valid[tid] = v ? 1.0f : 0.0f;
    }
    __syncthreads();

    // Phase 2: each thread owns 4 consecutive emb channels; 4 rows per iter.
    // Non-temporal stores: avoid L2 read-for-ownership on the pure write stream.
    const int e4   = tid & 63;
    const int ssub = tid >> 6;
    const float4 A4 = *reinterpret_cast<const float4*>(&sA[e4 * 4]);
    const float4 B4 = *reinterpret_cast<const float4*>(&sB[e4 * 4]);
    const float4 C4 = *reinterpret_cast<const float4*>(&sC[e4 * 4]);
    const float4 D4 = *reinterpret_cast<const float4*>(&sD[e4 * 4]);

    vf4* __restrict__ out4 = reinterpret_cast<vf4*>(out) + (size_t)b * SEQ * (EMB / 4);
    #pragma unroll 2
    for (int s0 = 0; s0 < SEQ; s0 += 4) {   // SEQ divisible by 4
        const int s = s0 + ssub;
        const float sk = s_skill[s];
        const float at = s_att[s];
        const float ma = s_mast[s];
        const float v  = s_valid[s];
        vf4 o;
        o.x = v * fmaf(sk, A4.x, fmaf(at, B4.x, fmaf(ma, C4.x, D4.x)));
        o.y = v * fmaf(sk, A4.y, fmaf(at, B4.y, fmaf(ma, C4.y, D4.y)));
        o.z = v * fmaf(sk, A4.z, fmaf(at, B4.z, fmaf(ma, C4.z, D4.z)));
        o.w = v * fmaf(sk, A4.w, fmaf(at, B4.w, fmaf(ma, C4.w, D4.w)));
        __builtin_nontemporal_store(o, &out4[(size_t)s * (EMB / 4) + e4]);
    }
}

extern "C" void kernel_launch(void* const* d_in, const int* in_sizes, int n_in,
                              void* d_out, int out_size, void* d_ws, size_t ws_size,
                              hipStream_t stream)
{
    const int* q        = (const int*)d_in[0];
    const int* r        = (const int*)d_in[1];
    // d_in[2] = qry (unused by the reference)
    const float* skill_w = (const float*)d_in[3];
    const float* skill_b = (const float*)d_in[4];
    const float* att_w   = (const float*)d_in[5];
    const float* att_b   = (const float*)d_in[6];
    const float* mast_w  = (const float*)d_in[7];
    const float* mast_b  = (const float*)d_in[8];
    const float* proj_w  = (const float*)d_in[9];
    const float* proj_b  = (const float*)d_in[10];
    float* out = (float*)d_out;

    const int B = in_sizes[0] / SEQ;  // 512
    traj_enc_kernel<<<B, 256, 0, stream>>>(q, r, skill_w, skill_b, att_w, att_b,
                                           mast_w, mast_b, proj_w, proj_b, out);
}

// Round 4
// 31.112 us; speedup vs baseline: 1.5950x; 1.0122x over previous
//
#include <hip/hip_runtime.h>

constexpr int NUM_SKILLS = 300;
constexpr int EMB = 256;
constexpr int CD  = 64;
constexpr int D3  = 21;   // CURVE_DIM // 3
constexpr int DM  = 22;   // D3 + CURVE_DIM % 3
constexpr int SEQ = 200;
constexpr int QUARTERS = 4;               // blocks per batch row
constexpr int ROWS_PB  = SEQ / QUARTERS;  // 50 rows per block

typedef float vf4 __attribute__((ext_vector_type(4)));

__global__ __launch_bounds__(256)
void traj_enc_kernel(const int* __restrict__ q, const int* __restrict__ r,
                     const float* __restrict__ skill_w, const float* __restrict__ skill_b,
                     const float* __restrict__ att_w,   const float* __restrict__ att_b,
                     const float* __restrict__ mast_w,  const float* __restrict__ mast_b,
                     const float* __restrict__ proj_w,  const float* __restrict__ proj_b,
                     float* __restrict__ out)
{
    __shared__ __align__(16) float sA[EMB];
    __shared__ __align__(16) float sB[EMB];
    __shared__ __align__(16) float sC[EMB];
    __shared__ __align__(16) float sD[EMB];
    __shared__ float s_sk[ROWS_PB], s_at[ROWS_PB], s_ma[ROWS_PB], s_va[ROWS_PB];
    __shared__ int   s_q[SEQ], s_r[SEQ];

    const int tid  = threadIdx.x;
    const int b    = blockIdx.x >> 2;         // batch row
    const int qs   = (blockIdx.x & 3) * ROWS_PB;  // first row this block owns

    // stage this batch's q/r rows (full prefix needed for running counts)
    if (tid < SEQ) {
        s_q[tid] = q[b * SEQ + tid];
        s_r[tid] = r[b * SEQ + tid];
    }

    // Phase 0: fold the three scalar encoders + biases into per-e coefficients.
    // traj[e] = skill*A[e] + attempts*B[e] + mastery*C[e] + D[e]
    {
        const vf4* pw4 = reinterpret_cast<const vf4*>(proj_w + tid * CD);
        vf4 W[16];
        #pragma unroll
        for (int i = 0; i < 16; ++i) W[i] = pw4[i];

        float ca = 0.f, cb = 0.f, cc = 0.f, cd = 0.f;
        #pragma unroll
        for (int i = 0; i < D3; ++i) { float w = W[i >> 2][i & 3];              ca = fmaf(w, skill_w[i], ca); cd = fmaf(w, skill_b[i], cd); }
        #pragma unroll
        for (int i = 0; i < D3; ++i) { float w = W[(D3 + i) >> 2][(D3 + i) & 3]; cb = fmaf(w, att_w[i],  cb);  cd = fmaf(w, att_b[i],  cd); }
        #pragma unroll
        for (int i = 0; i < DM; ++i) { float w = W[(2*D3 + i) >> 2][(2*D3 + i) & 3]; cc = fmaf(w, mast_w[i], cc); cd = fmaf(w, mast_b[i], cd); }
        sA[tid] = ca; sB[tid] = cb; sC[tid] = cc; sD[tid] = cd + proj_b[tid];
    }
    __syncthreads();

    // Phase 1: running counts for this block's 50 rows.
    // attempts[t] = #{t'<=t : valid(q[t']) && q[t']==q[t]}
    if (tid < ROWS_PB) {
        const int row = qs + tid;
        const int myq = s_q[row];
        const bool v  = (myq >= 0) && (myq < NUM_SKILLS);
        int cnt = 0, cor = 0;
        for (int t = 0; t <= row; ++t) {
            const bool m = (s_q[t] == myq) && v;
            cnt += m ? 1 : 0;
            cor += m ? s_r[t] : 0;
        }
        const float att = (float)cnt;
        s_sk[tid] = (float)myq;
        s_at[tid] = att;
        s_ma[tid] = (float)cor / fmaxf(att, 1.0f);
        s_va[tid] = v ? 1.0f : 0.0f;
    }
    __syncthreads();

    // Phase 2: stream 50 rows x 256 channels. Thread (ssub, e4) covers
    // 4 consecutive emb channels; rows advance 4 at a time (+2 ragged).
    const int e4   = tid & 63;
    const int ssub = tid >> 6;
    const float4 A4 = *reinterpret_cast<const float4*>(&sA[e4 * 4]);
    const float4 B4 = *reinterpret_cast<const float4*>(&sB[e4 * 4]);
    const float4 C4 = *reinterpret_cast<const float4*>(&sC[e4 * 4]);
    const float4 D4 = *reinterpret_cast<const float4*>(&sD[e4 * 4]);

    vf4* __restrict__ out4 = reinterpret_cast<vf4*>(out)
                           + (size_t)(b * SEQ + qs) * (EMB / 4);

    #pragma unroll 3
    for (int s0 = 0; s0 + 4 <= ROWS_PB; s0 += 4) {
        const int s = s0 + ssub;
        const float sk = s_sk[s], at = s_at[s], ma = s_ma[s], v = s_va[s];
        vf4 o;
        o.x = v * fmaf(sk, A4.x, fmaf(at, B4.x, fmaf(ma, C4.x, D4.x)));
        o.y = v * fmaf(sk, A4.y, fmaf(at, B4.y, fmaf(ma, C4.y, D4.y)));
        o.z = v * fmaf(sk, A4.z, fmaf(at, B4.z, fmaf(ma, C4.z, D4.z)));
        o.w = v * fmaf(sk, A4.w, fmaf(at, B4.w, fmaf(ma, C4.w, D4.w)));
        __builtin_nontemporal_store(o, &out4[(size_t)s * (EMB / 4) + e4]);
    }
    // ragged tail: rows 48, 49 (ROWS_PB = 50)
    if (ssub < 2) {
        const int s = 48 + ssub;
        const float sk = s_sk[s], at = s_at[s], ma = s_ma[s], v = s_va[s];
        vf4 o;
        o.x = v * fmaf(sk, A4.x, fmaf(at, B4.x, fmaf(ma, C4.x, D4.x)));
        o.y = v * fmaf(sk, A4.y, fmaf(at, B4.y, fmaf(ma, C4.y, D4.y)));
        o.z = v * fmaf(sk, A4.z, fmaf(at, B4.z, fmaf(ma, C4.z, D4.z)));
        o.w = v * fmaf(sk, A4.w, fmaf(at, B4.w, fmaf(ma, C4.w, D4.w)));
        __builtin_nontemporal_store(o, &out4[(size_t)s * (EMB / 4) + e4]);
    }
}

extern "C" void kernel_launch(void* const* d_in, const int* in_sizes, int n_in,
                              void* d_out, int out_size, void* d_ws, size_t ws_size,
                              hipStream_t stream)
{
    const int* q        = (const int*)d_in[0];
    const int* r        = (const int*)d_in[1];
    // d_in[2] = qry (unused by the reference)
    const float* skill_w = (const float*)d_in[3];
    const float* skill_b = (const float*)d_in[4];
    const float* att_w   = (const float*)d_in[5];
    const float* att_b   = (const float*)d_in[6];
    const float* mast_w  = (const float*)d_in[7];
    const float* mast_b  = (const float*)d_in[8];
    const float* proj_w  = (const float*)d_in[9];
    const float* proj_b  = (const float*)d_in[10];
    float* out = (float*)d_out;

    const int B = in_sizes[0] / SEQ;  // 512
    traj_enc_kernel<<<B * QUARTERS, 256, 0, stream>>>(q, r, skill_w, skill_b,
                                                      att_w, att_b, mast_w, mast_b,
                                                      proj_w, proj_b, out);
}